// Round 13
// baseline (300.314 us; speedup 1.0000x reference)
//
#include <hip/hip_runtime.h>
#include <math.h>

// Problem constants (B, N, TF, DM) = (16, 4096, 512, 1024)
#define B_DIM 16
#define N_SEQ 4096
#define TF_DIM 512
#define DM_DIM 1024
#define CHUNK 128
#define NCHUNK (N_SEQ / CHUNK)   // 32
#define NT 32                    // K-tiles of BK=32 (K=1024)

typedef __attribute__((ext_vector_type(4))) float f32x4;
typedef __attribute__((ext_vector_type(8))) short bf16x8;
typedef unsigned short u16;
typedef unsigned int u32;

__device__ __forceinline__ u16 f2bf(float f) {
    u32 u = __builtin_bit_cast(u32, f);
    u += 0x7fffu + ((u >> 16) & 1u);
    return (u16)(u >> 16);
}

__device__ __forceinline__ u32 cvtpk(float lo, float hi) {
    u32 r;
    asm("v_cvt_pk_bf16_f32 %0, %1, %2" : "=v"(r) : "v"(lo), "v"(hi));
    return r;
}

__device__ __forceinline__ void gload16(const u16* g, u16* l) {
    __builtin_amdgcn_global_load_lds(
        (const __attribute__((address_space(1))) void*)g,
        (__attribute__((address_space(3))) void*)l, 16, 0, 0);
}

// Counted waits: NEVER drain vmcnt to 0 inside the main loop (T4).
#define WAIT8_BAR() asm volatile("s_waitcnt vmcnt(8)\n\ts_barrier" ::: "memory")
#define WAIT4_BAR() asm volatile("s_waitcnt vmcnt(4)\n\ts_barrier" ::: "memory")
#define WAIT0_BAR() asm volatile("s_waitcnt vmcnt(0)\n\ts_barrier" ::: "memory")

// ---------------------------------------------------------------------------
// K0: fp32 -> bf16 PACK into tile-order images — COALESCED version.
// One 256-thread block per 16 KB blob (panel p, K-tile t). Thread = row:
// reads the row's 128B source window (4 x 32B, granule-permuted), writes the
// row's 64B destination line CONTIGUOUSLY (1 full cache line per thread;
// wave = 16 KB contiguous). Round-12 pack scattered 16B writes across blobs
// (~4x write amplification) — that was the R12 regression, not the gemm.
// Mapping identical to R12 (validated by the passing gemm):
//   dst = blob(p,t)*8192 + row*32 + gp*8,  gp = g ^ (row&3) ^ ((row>>2)&3)
// ---------------------------------------------------------------------------
__global__ __launch_bounds__(256)
void pack_bf16(const float* __restrict__ ls, const float* __restrict__ wmat,
               u16* __restrict__ lsb, u16* __restrict__ wmb)
{
    const int bid = blockIdx.x;
    const int row = threadIdx.x;            // 0..255
    const float* src;
    u16* dstBlob;
    int t;
    if (bid < 8192) {                       // latent_seasonal: 256 panels x 32
        const int rp = bid >> 5; t = bid & 31;
        src = ls + ((size_t)(rp * 256 + row) << 10);
        dstBlob = lsb + (((size_t)bid) << 13);
    } else {                                // w_seasonal: 2 panels x 32
        const int j = bid - 8192;
        const int fb = j >> 5; t = j & 31;
        src = wmat + ((size_t)(fb * 256 + row) << 10);
        dstBlob = wmb + (((size_t)j) << 13);
    }
    u16* drow = dstBlob + row * 32;
    const int px = (row & 3) ^ ((row >> 2) & 3);
#pragma unroll
    for (int g = 0; g < 4; ++g) {
        const int gp = g ^ px;
        const f32x4 v0 = *(const f32x4*)(src + t * 32 + g * 8);
        const f32x4 v1 = *(const f32x4*)(src + t * 32 + g * 8 + 4);
        u32* d = (u32*)(drow + gp * 8);
        d[0] = cvtpk(v0[0], v0[1]);
        d[1] = cvtpk(v0[2], v0[3]);
        d[2] = cvtpk(v1[0], v1[1]);
        d[3] = cvtpk(v1[2], v1[3]);
    }
}

// ---------------------------------------------------------------------------
// K1: 256x256 tile, BK=32, 8 waves (2M x 4N), per-wave output 128x64,
// acc[8][4], mfma_f32_16x16x32_bf16. QUAD-buffered LDS (4 x 32 KB), loads
// staged 3 TILES AHEAD via global_load_lds from the packed image; per tile:
//   s_waitcnt vmcnt(8)  (only this tile's 4 loads; 8 stay in flight)
//   s_barrier ; stage tile t+3 ; 12 ds_read_b128 ; 32 MFMA
// vmcnt never reaches 0 in the loop. UNCHANGED from round 12 (passing,
// best-yet K-loop ~130 µs inferred).
// ---------------------------------------------------------------------------
__global__ __launch_bounds__(512, 2)
void gemm_u_kernel(const float* __restrict__ x,
                   const u16* __restrict__ lsb,
                   const u16* __restrict__ wmb,
                   const float* __restrict__ bias,
                   const float* __restrict__ alpha,
                   u16* __restrict__ u,
                   float* __restrict__ e)
{
    __shared__ u16 As[4][8192];   // 64 KB
    __shared__ u16 Ws[4][8192];   // 64 KB

    const int tid = threadIdx.x;

    // XCD remap: 2 f-siblings of each A-row-panel consecutive on one XCD
    const int s  = blockIdx.x;                  // 0..511
    const int kk = s >> 3;
    const int fb = kk & 1;
    const int rp = (s & 7) + ((kk >> 1) << 3);  // 0..255
    const int f0   = fb * 256;
    const int row0 = rp * 256;

    const int lane = tid & 63;
    const int wid  = tid >> 6;          // 0..7
    const int wm = wid >> 2;            // M half
    const int wn = wid & 3;             // N quarter
    const int l15 = lane & 15, l4 = lane >> 4;

    // packed-image bases; staging is fully linear
    const u16* pa = lsb + ((size_t)rp << 18);   // rp * 32*8192
    const u16* pw = wmb + ((size_t)fb << 18);
    const int qa   = (wid * 128 + lane) * 8;    // my granule (u16 units)
    const int ldsb = wid * 1024;                // wave-uniform LDS base (u16)

#define STG(NB, T) do {                                                   \
        const size_t _b = ((size_t)(T)) << 13;                            \
        gload16(pa + _b + qa,       &As[NB][ldsb]);                       \
        gload16(pa + _b + qa + 512, &As[NB][ldsb + 512]);                 \
        gload16(pw + _b + qa,       &Ws[NB][ldsb]);                       \
        gload16(pw + _b + qa + 512, &Ws[NB][ldsb + 512]);                 \
    } while (0)

    // fragment read offsets (u16), swizzle baked into the image
    int rofa[8], rofw[4];
#pragma unroll
    for (int mi = 0; mi < 8; ++mi) {
        const int ra = wm * 128 + mi * 16 + l15;
        rofa[mi] = ra * 32 + ((l4 ^ (ra & 3) ^ ((ra >> 2) & 3)) * 8);
    }
#pragma unroll
    for (int ni = 0; ni < 4; ++ni) {
        const int rw = wn * 64 + ni * 16 + l15;
        rofw[ni] = rw * 32 + ((l4 ^ (rw & 3) ^ ((rw >> 2) & 3)) * 8);
    }

    f32x4 acc[8][4];
#pragma unroll
    for (int i = 0; i < 8; ++i)
#pragma unroll
        for (int j = 0; j < 4; ++j) acc[i][j] = (f32x4){0.f, 0.f, 0.f, 0.f};

#define COMPUTE(BUF) do {                                                 \
        const u16* _Ab = As[BUF];                                         \
        const u16* _Wb = Ws[BUF];                                         \
        bf16x8 _af[8], _wf[4];                                            \
        _Pragma("unroll")                                                 \
        for (int mi = 0; mi < 8; ++mi)                                    \
            _af[mi] = *(const bf16x8*)(_Ab + rofa[mi]);                   \
        _Pragma("unroll")                                                 \
        for (int ni = 0; ni < 4; ++ni)                                    \
            _wf[ni] = *(const bf16x8*)(_Wb + rofw[ni]);                   \
        __builtin_amdgcn_s_setprio(1);                                    \
        _Pragma("unroll")                                                 \
        for (int mi = 0; mi < 8; ++mi)                                    \
        _Pragma("unroll")                                                 \
        for (int ni = 0; ni < 4; ++ni)                                    \
            acc[mi][ni] = __builtin_amdgcn_mfma_f32_16x16x32_bf16(        \
                _af[mi], _wf[ni], acc[mi][ni], 0, 0, 0);                  \
        __builtin_amdgcn_s_setprio(0);                                    \
    } while (0)

    // prologue: 3 tiles in flight (12 loads)
    STG(0, 0);
    STG(1, 1);
    STG(2, 2);

#pragma unroll 1
    for (int t = 0; t < NT - 2; ++t) {         // t = 0..29
        WAIT8_BAR();                            // tile t landed; 8 stay out
        if (t + 3 < NT) STG((t + 3) & 3, t + 3);
        COMPUTE(t & 3);
    }
    // t = 30: outstanding = tiles 30,31 (8 loads) -> wait 4
    WAIT4_BAR();
    COMPUTE(2);
    // t = 31
    WAIT0_BAR();
    COMPUTE(3);

    // epilogue: u = 2x - (acc + bias) (bf16); chunk-end EMA.
    const float a = 1.0f / (1.0f + expf(-alpha[0]));
    const float c = 1.0f - a;
    const float l2c = log2f(c);

    float bia[4];
#pragma unroll
    for (int ni = 0; ni < 4; ++ni) bia[ni] = bias[f0 + wn * 64 + ni * 16 + l15];

    float epart[4] = {0.f, 0.f, 0.f, 0.f};

#pragma unroll
    for (int mi = 0; mi < 8; ++mi) {
#pragma unroll
        for (int j = 0; j < 4; ++j) {
            const int rc = mi * 16 + l4 * 4 + j;            // row in chunk
            const int r  = wm * 128 + rc;                   // row in block
            const size_t rb = (size_t)(row0 + r) * TF_DIM;
            const float wgt = (rc == CHUNK - 1)
                                  ? a
                                  : a * exp2f((float)(CHUNK - 1 - rc) * l2c);
#pragma unroll
            for (int ni = 0; ni < 4; ++ni) {
                const int f = f0 + wn * 64 + ni * 16 + l15;
                const float uval = 2.0f * x[rb + f] - (acc[mi][ni][j] + bia[ni]);
                u[rb + f] = f2bf(uval);
                epart[ni] = fmaf(wgt, uval, epart[ni]);
            }
        }
    }

#pragma unroll
    for (int ni = 0; ni < 4; ++ni) {
        epart[ni] += __shfl_xor(epart[ni], 16, 64);
        epart[ni] += __shfl_xor(epart[ni], 32, 64);
    }
    if (l4 == 0) {
#pragma unroll
        for (int ni = 0; ni < 4; ++ni) {
            const int f = f0 + wn * 64 + ni * 16 + l15;
            e[(size_t)(rp * 2 + wm) * TF_DIM + f] = epart[ni];
        }
    }
}

// ---------------------------------------------------------------------------
// K3: serial carry scan over chunks per (b,f)
// ---------------------------------------------------------------------------
__global__ __launch_bounds__(256)
void ema_carry(const float* __restrict__ e, const float* __restrict__ alpha,
               float* __restrict__ carry)
{
    const int idx = blockIdx.x * 256 + threadIdx.x;
    const int f = idx & (TF_DIM - 1);
    const int b = idx >> 9;
    const float a = 1.0f / (1.0f + expf(-alpha[0]));
    const float c = 1.0f - a;
    const float cC = exp2f((float)CHUNK * log2f(c));
    const size_t base = (size_t)b * NCHUNK * TF_DIM + f;
    float Y = 0.0f;
    carry[base] = 0.0f;
    for (int ch = 1; ch < NCHUNK; ++ch) {
        Y = fmaf(cC, Y, e[base + (size_t)(ch - 1) * TF_DIM]);
        carry[base + (size_t)ch * TF_DIM] = Y;
    }
}

// ---------------------------------------------------------------------------
// K4: apply chunk-local EMA with carry-in (u bf16, 2 cols/thread)
// ---------------------------------------------------------------------------
__global__ __launch_bounds__(256)
void ema_apply(const u16* __restrict__ u, const float* __restrict__ carry,
               const float* __restrict__ alpha, float* __restrict__ out)
{
    const int bc = blockIdx.x;
    const int tid = threadIdx.x;
    const float a = 1.0f / (1.0f + expf(-alpha[0]));
    const float c = 1.0f - a;
    float y0 = carry[(size_t)bc * TF_DIM + 2 * tid];
    float y1 = carry[(size_t)bc * TF_DIM + 2 * tid + 1];
    const u32* up = (const u32*)(u + (size_t)bc * CHUNK * TF_DIM) + tid;
    float2*    op = (float2*)(out + (size_t)bc * CHUNK * TF_DIM) + tid;
#pragma unroll 4
    for (int j = 0; j < CHUNK; ++j) {
        const u32 w = up[(size_t)j * (TF_DIM / 2)];
        const float u0 = __builtin_bit_cast(float, (w & 0xffffu) << 16);
        const float u1 = __builtin_bit_cast(float, (w >> 16) << 16);
        y0 = fmaf(c, y0, a * u0);
        y1 = fmaf(c, y1, a * u1);
        op[(size_t)j * (TF_DIM / 2)] = make_float2(y0, y1);
    }
}

extern "C" void kernel_launch(void* const* d_in, const int* in_sizes, int n_in,
                              void* d_out, int out_size, void* d_ws, size_t ws_size,
                              hipStream_t stream) {
    // setup_inputs order: x, latent_growth, latent_seasonal, alpha,
    //                     w_growth, b_growth, w_seasonal, b_seasonal
    const float* x     = (const float*)d_in[0];
    const float* ls    = (const float*)d_in[2];
    const float* alpha = (const float*)d_in[3];
    const float* wmat  = (const float*)d_in[6];
    const float* bias  = (const float*)d_in[7];
    float* out = (float*)d_out;

    // workspace layout (16B-aligned)
    u16*   u     = (u16*)d_ws;                                 // 64 MiB bf16 u
    u16*   lsb   = u + (size_t)B_DIM * N_SEQ * TF_DIM;         // 128 MiB packed
    u16*   wmb   = lsb + (size_t)B_DIM * N_SEQ * DM_DIM;       // 1 MiB packed
    float* e     = (float*)(wmb + (size_t)2 * 32 * 8192);      // 1 MiB
    float* carry = e + (size_t)B_DIM * NCHUNK * TF_DIM;        // 1 MiB

    // K0: pack+convert ls and wmat into tile-order bf16 images (coalesced)
    pack_bf16<<<8192 + 64, 256, 0, stream>>>(ls, wmat, lsb, wmb);

    // K1: GEMM + u + chunk-end EMA (512 blocks of 512 threads)
    gemm_u_kernel<<<512, 512, 0, stream>>>(x, lsb, wmb, bias, alpha, u, e);

    ema_carry<<<(B_DIM * TF_DIM) / 256, 256, 0, stream>>>(e, alpha, carry);
    ema_apply<<<B_DIM * NCHUNK, 256, 0, stream>>>(u, carry, alpha, out);
}

// Round 14
// 264.937 us; speedup vs baseline: 1.1335x; 1.1335x over previous
//
#include <hip/hip_runtime.h>
#include <math.h>

// Problem constants (B, N, TF, DM) = (16, 4096, 512, 1024)
#define B_DIM 16
#define N_SEQ 4096
#define TF_DIM 512
#define DM_DIM 1024
#define CHUNK 128
#define NCHUNK (N_SEQ / CHUNK)   // 32
#define NT 32                    // K-tiles of BK=32 (K=1024)

typedef __attribute__((ext_vector_type(4))) float f32x4;
typedef __attribute__((ext_vector_type(8))) short bf16x8;
typedef unsigned short u16;
typedef unsigned int u32;

__device__ __forceinline__ u16 f2bf(float f) {
    u32 u = __builtin_bit_cast(u32, f);
    u += 0x7fffu + ((u >> 16) & 1u);
    return (u16)(u >> 16);
}

__device__ __forceinline__ u32 cvtpk(float lo, float hi) {
    u32 r;
    asm("v_cvt_pk_bf16_f32 %0, %1, %2" : "=v"(r) : "v"(lo), "v"(hi));
    return r;
}

__device__ __forceinline__ void gload16(const u16* g, u16* l) {
    __builtin_amdgcn_global_load_lds(
        (const __attribute__((address_space(1))) void*)g,
        (__attribute__((address_space(3))) void*)l, 16, 0, 0);
}

// Counted waits: NEVER drain vmcnt to 0 inside the main loop (T4).
#define WAIT8_BAR() asm volatile("s_waitcnt vmcnt(8)\n\ts_barrier" ::: "memory")
#define WAIT4_BAR() asm volatile("s_waitcnt vmcnt(4)\n\ts_barrier" ::: "memory")
#define WAIT0_BAR() asm volatile("s_waitcnt vmcnt(0)\n\ts_barrier" ::: "memory")

// ---------------------------------------------------------------------------
// K0: fp32 -> bf16 PACK into tile-order images — LDS-TRANSPOSE version.
// R12 pack: coalesced reads, 16B-scattered writes (~4x write amp, ~105us).
// R13 pack: 4KB-strided reads -> HBM channel camping (0.88 TB/s, 154us).
// R14: block = one (panel, 32-row group). READ 128 KB fully contiguous
// (wave = 2 KB sequential), convert, stage in LDS (row stride padded to 129
// granules -> uniform 8-lanes-per-4-bank-group on both b128 write and read,
// i.e. conflict-free), then WRITE 32 x 2 KB contiguous chunks into the blob
// layout the gemm already consumes:
//   blob(p,t)*8192 + row*32 + gp*8,  gp = g ^ (row&3) ^ ((row>>2)&3)
// (px depends only on row%32, so the 32-row group decomposition is exact).
// ---------------------------------------------------------------------------
__global__ __launch_bounds__(256)
void pack_bf16(const float* __restrict__ ls, const float* __restrict__ wmat,
               u16* __restrict__ lsb, u16* __restrict__ wmb)
{
    __shared__ u16 sb[32 * 129 * 8];   // 66 KB, padded row stride
    const int bid = blockIdx.x;
    const int tid = threadIdx.x;
    const float* srcBase;
    u16* dstBase;    // panel image base + row-group offset
    if (bid < 2048) {                       // latent_seasonal: 256 x 8 groups
        const int rp = bid >> 3, rg = bid & 7;
        srcBase = ls + ((size_t)(rp * 256 + rg * 32) << 10);
        dstBase = lsb + ((size_t)rp << 18) + rg * 1024;
    } else {                                // w_seasonal: 2 x 8 groups
        const int j = bid - 2048;
        const int fb = j >> 3, rg = j & 7;
        srcBase = wmat + ((size_t)(fb * 256 + rg * 32) << 10);
        dstBase = wmb + ((size_t)fb << 18) + rg * 1024;
    }

    // read phase: 128 KB contiguous; granule G = 32B of one row
#pragma unroll
    for (int it = 0; it < 16; ++it) {
        const int G = it * 256 + tid;       // 0..4095
        const int rL = G >> 7, g = G & 127; // row-in-group, granule-in-row
        const float* s = srcBase + ((size_t)rL << 10) + g * 8;
        const f32x4 v0 = *(const f32x4*)s;
        const f32x4 v1 = *(const f32x4*)(s + 4);
        union { u32 u[4]; bf16x8 v; } p;
        p.u[0] = cvtpk(v0[0], v0[1]);
        p.u[1] = cvtpk(v0[2], v0[3]);
        p.u[2] = cvtpk(v1[0], v1[1]);
        p.u[3] = cvtpk(v1[2], v1[3]);
        *(bf16x8*)&sb[(rL * 129 + g) * 8] = p.v;
    }
    __syncthreads();

    // write phase: 32 chunks of 2 KB, each contiguous (wave = 1 KB seq.)
#pragma unroll
    for (int it = 0; it < 16; ++it) {
        const int w = it * 256 + tid;       // 0..4095
        const int t = w >> 7, i = w & 127;  // tile, granule-in-chunk
        const int rowL = i >> 2, gp = i & 3;
        const int gq = gp ^ (rowL & 3) ^ ((rowL >> 2) & 3);
        const bf16x8 v = *(const bf16x8*)&sb[(rowL * 129 + t * 4 + gq) * 8];
        *(bf16x8*)(dstBase + (((size_t)t) << 13) + i * 8) = v;
    }
}

// ---------------------------------------------------------------------------
// K1: 256x256 tile, BK=32, 8 waves (2M x 4N), per-wave output 128x64,
// acc[8][4], mfma_f32_16x16x32_bf16. QUAD-buffered LDS (4 x 32 KB), loads
// staged 3 TILES AHEAD via global_load_lds from the packed image; per tile:
//   s_waitcnt vmcnt(8) ; s_barrier ; stage tile t+3 ; 12 ds_read ; 32 MFMA
// vmcnt never reaches 0 in the loop. UNCHANGED from rounds 12/13 (passing,
// ~110-130 us inferred — best K-loop so far).
// ---------------------------------------------------------------------------
__global__ __launch_bounds__(512, 2)
void gemm_u_kernel(const float* __restrict__ x,
                   const u16* __restrict__ lsb,
                   const u16* __restrict__ wmb,
                   const float* __restrict__ bias,
                   const float* __restrict__ alpha,
                   u16* __restrict__ u,
                   float* __restrict__ e)
{
    __shared__ u16 As[4][8192];   // 64 KB
    __shared__ u16 Ws[4][8192];   // 64 KB

    const int tid = threadIdx.x;

    // XCD remap: 2 f-siblings of each A-row-panel consecutive on one XCD
    const int s  = blockIdx.x;                  // 0..511
    const int kk = s >> 3;
    const int fb = kk & 1;
    const int rp = (s & 7) + ((kk >> 1) << 3);  // 0..255
    const int f0   = fb * 256;
    const int row0 = rp * 256;

    const int lane = tid & 63;
    const int wid  = tid >> 6;          // 0..7
    const int wm = wid >> 2;            // M half
    const int wn = wid & 3;             // N quarter
    const int l15 = lane & 15, l4 = lane >> 4;

    // packed-image bases; staging is fully linear
    const u16* pa = lsb + ((size_t)rp << 18);   // rp * 32*8192
    const u16* pw = wmb + ((size_t)fb << 18);
    const int qa   = (wid * 128 + lane) * 8;    // my granule (u16 units)
    const int ldsb = wid * 1024;                // wave-uniform LDS base (u16)

#define STG(NB, T) do {                                                   \
        const size_t _b = ((size_t)(T)) << 13;                            \
        gload16(pa + _b + qa,       &As[NB][ldsb]);                       \
        gload16(pa + _b + qa + 512, &As[NB][ldsb + 512]);                 \
        gload16(pw + _b + qa,       &Ws[NB][ldsb]);                       \
        gload16(pw + _b + qa + 512, &Ws[NB][ldsb + 512]);                 \
    } while (0)

    // fragment read offsets (u16), swizzle baked into the image
    int rofa[8], rofw[4];
#pragma unroll
    for (int mi = 0; mi < 8; ++mi) {
        const int ra = wm * 128 + mi * 16 + l15;
        rofa[mi] = ra * 32 + ((l4 ^ (ra & 3) ^ ((ra >> 2) & 3)) * 8);
    }
#pragma unroll
    for (int ni = 0; ni < 4; ++ni) {
        const int rw = wn * 64 + ni * 16 + l15;
        rofw[ni] = rw * 32 + ((l4 ^ (rw & 3) ^ ((rw >> 2) & 3)) * 8);
    }

    f32x4 acc[8][4];
#pragma unroll
    for (int i = 0; i < 8; ++i)
#pragma unroll
        for (int j = 0; j < 4; ++j) acc[i][j] = (f32x4){0.f, 0.f, 0.f, 0.f};

#define COMPUTE(BUF) do {                                                 \
        const u16* _Ab = As[BUF];                                         \
        const u16* _Wb = Ws[BUF];                                         \
        bf16x8 _af[8], _wf[4];                                            \
        _Pragma("unroll")                                                 \
        for (int mi = 0; mi < 8; ++mi)                                    \
            _af[mi] = *(const bf16x8*)(_Ab + rofa[mi]);                   \
        _Pragma("unroll")                                                 \
        for (int ni = 0; ni < 4; ++ni)                                    \
            _wf[ni] = *(const bf16x8*)(_Wb + rofw[ni]);                   \
        __builtin_amdgcn_s_setprio(1);                                    \
        _Pragma("unroll")                                                 \
        for (int mi = 0; mi < 8; ++mi)                                    \
        _Pragma("unroll")                                                 \
        for (int ni = 0; ni < 4; ++ni)                                    \
            acc[mi][ni] = __builtin_amdgcn_mfma_f32_16x16x32_bf16(        \
                _af[mi], _wf[ni], acc[mi][ni], 0, 0, 0);                  \
        __builtin_amdgcn_s_setprio(0);                                    \
    } while (0)

    // prologue: 3 tiles in flight (12 loads)
    STG(0, 0);
    STG(1, 1);
    STG(2, 2);

#pragma unroll 1
    for (int t = 0; t < NT - 2; ++t) {         // t = 0..29
        WAIT8_BAR();                            // tile t landed; 8 stay out
        if (t + 3 < NT) STG((t + 3) & 3, t + 3);
        COMPUTE(t & 3);
    }
    // t = 30: outstanding = tiles 30,31 (8 loads) -> wait 4
    WAIT4_BAR();
    COMPUTE(2);
    // t = 31
    WAIT0_BAR();
    COMPUTE(3);

    // epilogue: u = 2x - (acc + bias) (bf16); chunk-end EMA.
    const float a = 1.0f / (1.0f + expf(-alpha[0]));
    const float c = 1.0f - a;
    const float l2c = log2f(c);

    float bia[4];
#pragma unroll
    for (int ni = 0; ni < 4; ++ni) bia[ni] = bias[f0 + wn * 64 + ni * 16 + l15];

    float epart[4] = {0.f, 0.f, 0.f, 0.f};

#pragma unroll
    for (int mi = 0; mi < 8; ++mi) {
#pragma unroll
        for (int j = 0; j < 4; ++j) {
            const int rc = mi * 16 + l4 * 4 + j;            // row in chunk
            const int r  = wm * 128 + rc;                   // row in block
            const size_t rb = (size_t)(row0 + r) * TF_DIM;
            const float wgt = (rc == CHUNK - 1)
                                  ? a
                                  : a * exp2f((float)(CHUNK - 1 - rc) * l2c);
#pragma unroll
            for (int ni = 0; ni < 4; ++ni) {
                const int f = f0 + wn * 64 + ni * 16 + l15;
                const float uval = 2.0f * x[rb + f] - (acc[mi][ni][j] + bia[ni]);
                u[rb + f] = f2bf(uval);
                epart[ni] = fmaf(wgt, uval, epart[ni]);
            }
        }
    }

#pragma unroll
    for (int ni = 0; ni < 4; ++ni) {
        epart[ni] += __shfl_xor(epart[ni], 16, 64);
        epart[ni] += __shfl_xor(epart[ni], 32, 64);
    }
    if (l4 == 0) {
#pragma unroll
        for (int ni = 0; ni < 4; ++ni) {
            const int f = f0 + wn * 64 + ni * 16 + l15;
            e[(size_t)(rp * 2 + wm) * TF_DIM + f] = epart[ni];
        }
    }
}

// ---------------------------------------------------------------------------
// K3: serial carry scan over chunks per (b,f)
// ---------------------------------------------------------------------------
__global__ __launch_bounds__(256)
void ema_carry(const float* __restrict__ e, const float* __restrict__ alpha,
               float* __restrict__ carry)
{
    const int idx = blockIdx.x * 256 + threadIdx.x;
    const int f = idx & (TF_DIM - 1);
    const int b = idx >> 9;
    const float a = 1.0f / (1.0f + expf(-alpha[0]));
    const float c = 1.0f - a;
    const float cC = exp2f((float)CHUNK * log2f(c));
    const size_t base = (size_t)b * NCHUNK * TF_DIM + f;
    float Y = 0.0f;
    carry[base] = 0.0f;
    for (int ch = 1; ch < NCHUNK; ++ch) {
        Y = fmaf(cC, Y, e[base + (size_t)(ch - 1) * TF_DIM]);
        carry[base + (size_t)ch * TF_DIM] = Y;
    }
}

// ---------------------------------------------------------------------------
// K4: apply chunk-local EMA with carry-in (u bf16, 2 cols/thread)
// ---------------------------------------------------------------------------
__global__ __launch_bounds__(256)
void ema_apply(const u16* __restrict__ u, const float* __restrict__ carry,
               const float* __restrict__ alpha, float* __restrict__ out)
{
    const int bc = blockIdx.x;
    const int tid = threadIdx.x;
    const float a = 1.0f / (1.0f + expf(-alpha[0]));
    const float c = 1.0f - a;
    float y0 = carry[(size_t)bc * TF_DIM + 2 * tid];
    float y1 = carry[(size_t)bc * TF_DIM + 2 * tid + 1];
    const u32* up = (const u32*)(u + (size_t)bc * CHUNK * TF_DIM) + tid;
    float2*    op = (float2*)(out + (size_t)bc * CHUNK * TF_DIM) + tid;
#pragma unroll 4
    for (int j = 0; j < CHUNK; ++j) {
        const u32 w = up[(size_t)j * (TF_DIM / 2)];
        const float u0 = __builtin_bit_cast(float, (w & 0xffffu) << 16);
        const float u1 = __builtin_bit_cast(float, (w >> 16) << 16);
        y0 = fmaf(c, y0, a * u0);
        y1 = fmaf(c, y1, a * u1);
        op[(size_t)j * (TF_DIM / 2)] = make_float2(y0, y1);
    }
}

extern "C" void kernel_launch(void* const* d_in, const int* in_sizes, int n_in,
                              void* d_out, int out_size, void* d_ws, size_t ws_size,
                              hipStream_t stream) {
    // setup_inputs order: x, latent_growth, latent_seasonal, alpha,
    //                     w_growth, b_growth, w_seasonal, b_seasonal
    const float* x     = (const float*)d_in[0];
    const float* ls    = (const float*)d_in[2];
    const float* alpha = (const float*)d_in[3];
    const float* wmat  = (const float*)d_in[6];
    const float* bias  = (const float*)d_in[7];
    float* out = (float*)d_out;

    // workspace layout (16B-aligned)
    u16*   u     = (u16*)d_ws;                                 // 64 MiB bf16 u
    u16*   lsb   = u + (size_t)B_DIM * N_SEQ * TF_DIM;         // 128 MiB packed
    u16*   wmb   = lsb + (size_t)B_DIM * N_SEQ * DM_DIM;       // 1 MiB packed
    float* e     = (float*)(wmb + (size_t)2 * 32 * 8192);      // 1 MiB
    float* carry = e + (size_t)B_DIM * NCHUNK * TF_DIM;        // 1 MiB

    // K0: pack+convert ls and wmat into tile-order bf16 images (LDS transpose)
    pack_bf16<<<2048 + 16, 256, 0, stream>>>(ls, wmat, lsb, wmb);

    // K1: GEMM + u + chunk-end EMA (512 blocks of 512 threads)
    gemm_u_kernel<<<512, 512, 0, stream>>>(x, lsb, wmb, bias, alpha, u, e);

    ema_carry<<<(B_DIM * TF_DIM) / 256, 256, 0, stream>>>(e, alpha, carry);
    ema_apply<<<B_DIM * NCHUNK, 256, 0, stream>>>(u, carry, alpha, out);
}